// Round 11
// baseline (318.737 us; speedup 1.0000x reference)
//
#include <hip/hip_runtime.h>
#include <hip/hip_bf16.h>

typedef __bf16 bf16;
typedef __attribute__((ext_vector_type(8))) __bf16 bf16x8;
typedef __attribute__((ext_vector_type(4))) __bf16 bf16x4;
typedef __attribute__((ext_vector_type(2))) __bf16 bf16x2;
typedef __attribute__((ext_vector_type(4))) float floatx4;
typedef __attribute__((ext_vector_type(16))) float floatx16;
typedef unsigned int u32;

#define MFMA16(a, b, c) __builtin_amdgcn_mfma_f32_16x16x32_bf16((a), (b), (c), 0, 0, 0)
#define MFMA32(a, b, c) __builtin_amdgcn_mfma_f32_32x32x16_bf16((a), (b), (c), 0, 0, 0)

#define DIM 384
#define T1 3136   // 56*56
#define T2 784    // 28*28
#define T2P 832   // padded t for Vt columns
#define B_ 8
#define EPSV 1e-5f

__device__ __forceinline__ void gload_lds16(const bf16* g, bf16* l) {
  __builtin_amdgcn_global_load_lds(
      (const __attribute__((address_space(1))) void*)g,
      (__attribute__((address_space(3))) void*)l, 16, 0, 0);
}

__device__ __forceinline__ u32 pk2(float a, float b) {
  bf16x2 t = (bf16x2){(bf16)a, (bf16)b};
  return *reinterpret_cast<u32*>(&t);
}

// ---------------- fused depthwise convs + BN + wcvt, 4x4 spatial tile --------------
// R14 (proven: -12 us): 4x4 output tile, halo in[6][6], kv 2x2 in every block.
__global__ void conv_fused_kernel(const float* __restrict__ x,
    const float* __restrict__ wqc, const float* __restrict__ gq, const float* __restrict__ bq,
    const float* __restrict__ mq, const float* __restrict__ vq,
    const float* __restrict__ wkc, const float* __restrict__ gk, const float* __restrict__ bk,
    const float* __restrict__ mk, const float* __restrict__ vk,
    const float* __restrict__ wvc, const float* __restrict__ gv, const float* __restrict__ bv,
    const float* __restrict__ mv, const float* __restrict__ vvv,
    bf16* __restrict__ qout, bf16* __restrict__ kout, bf16* __restrict__ vout,
    const float* __restrict__ w0, const float* __restrict__ w1,
    const float* __restrict__ w2, const float* __restrict__ w3,
    bf16* __restrict__ d0, bf16* __restrict__ d1,
    bf16* __restrict__ d2, bf16* __restrict__ d3) {
  int blk = blockIdx.x;
  int c = threadIdx.x;           // 0..383
  int gid = blk * DIM + c;
  if (gid < 147456) {            // folded weight conversion (first 384 blocks)
    d0[gid] = (bf16)w0[gid]; d1[gid] = (bf16)w1[gid];
    d2[gid] = (bf16)w2[gid]; d3[gid] = (bf16)w3[gid];
  }
  int xg = blk % 14;
  int yg = (blk / 14) % 14;
  int b = blk / 196;
  int x0 = xg * 4, y0 = yg * 4;
  const float* xb = x + (size_t)b * T1 * DIM;
  float in[6][6];
#pragma unroll
  for (int r = 0; r < 6; ++r) {
    int yy = y0 + r - 1;
#pragma unroll
    for (int cc = 0; cc < 6; ++cc) {
      int xc = x0 + cc - 1;
      in[r][cc] = (yy >= 0 && yy < 56 && xc >= 0 && xc < 56)
                      ? xb[(yy * 56 + xc) * DIM + c] : 0.f;
    }
  }
  // q path: 4x4 outputs
  {
    float wr[9];
#pragma unroll
    for (int i = 0; i < 9; ++i) wr[i] = wqc[c * 9 + i];
    float a = rsqrtf(vq[c] + EPSV) * gq[c];
    float bia = bq[c] - mq[c] * a;
#pragma unroll
    for (int py = 0; py < 4; ++py) {
#pragma unroll
      for (int px = 0; px < 4; ++px) {
        float s = 0.f;
#pragma unroll
        for (int r = 0; r < 3; ++r)
#pragma unroll
          for (int dx = 0; dx < 3; ++dx) s += in[py + r][px + dx] * wr[r * 3 + dx];
        qout[((size_t)b * T1 + (y0 + py) * 56 + x0 + px) * DIM + c] = (bf16)(s * a + bia);
      }
    }
  }
  // kv path: 2x2 stride-2 outputs (y0, x0 even)
  {
    float wk9[9], wv9[9];
#pragma unroll
    for (int i = 0; i < 9; ++i) { wk9[i] = wkc[c * 9 + i]; wv9[i] = wvc[c * 9 + i]; }
    float ak = rsqrtf(vk[c] + EPSV) * gk[c];
    float av = rsqrtf(vvv[c] + EPSV) * gv[c];
    float bik = bk[c] - mk[c] * ak;
    float biv = bv[c] - mv[c] * av;
#pragma unroll
    for (int py = 0; py < 2; ++py) {
#pragma unroll
      for (int px = 0; px < 2; ++px) {
        float sk = 0.f, sv = 0.f;
#pragma unroll
        for (int r = 0; r < 3; ++r)
#pragma unroll
          for (int dx = 0; dx < 3; ++dx) {
            float xv = in[2 * py + r][2 * px + dx];
            sk += xv * wk9[r * 3 + dx];
            sv += xv * wv9[r * 3 + dx];
          }
        size_t o = ((size_t)b * T2 + (y0 / 2 + py) * 28 + (x0 / 2 + px)) * DIM + c;
        kout[o] = (bf16)(sk * ak + bik);
        vout[o] = (bf16)(sv * av + biv);
      }
    }
  }
}

// ---------------- shared GEMM body: C[128,128] tile of A[M,384] @ W[384,384]^T ------
// R15 (best measured): depth-2 staging, triple-buffered LDS, vmcnt(8) steady state.
#define BK 32
#define BUFSZ (128 * BK)
__device__ __forceinline__
void gemm_body(const bf16* A, const bf16* Bw, void* out, const float* bias,
               int mode, float scale, int m0, int n0, bf16* Al, bf16* Bl) {
  int tid = threadIdx.x;
  int w = tid >> 6, lane = tid & 63;
  int wm = w >> 1, wn = w & 1;
  int l16 = lane & 15, quad = lane >> 4;
  floatx4 acc[4][4];
#pragma unroll
  for (int i = 0; i < 4; ++i)
#pragma unroll
    for (int j = 0; j < 4; ++j) acc[i][j] = (floatx4){0.f, 0.f, 0.f, 0.f};

  int srow = w * 32 + (lane >> 2);
  int scol = (lane & 3) * 8;
  const bf16* ag0 = &A[(size_t)(m0 + srow) * DIM + scol];
  const bf16* ag1 = ag0 + (size_t)16 * DIM;
  const bf16* bg0 = &Bw[(size_t)(n0 + srow) * DIM + scol];
  const bf16* bg1 = bg0 + (size_t)16 * DIM;
  int lofs0 = (w * 32) * BK;
  int lofs1 = (w * 32 + 16) * BK;

#define STAGE_Q(s) {                                   \
    bf16* an = Al + ((s) % 3) * BUFSZ;                 \
    bf16* bn = Bl + ((s) % 3) * BUFSZ;                 \
    const int kk = (s) * BK;                           \
    gload_lds16(ag0 + kk, an + lofs0);                 \
    gload_lds16(ag1 + kk, an + lofs1);                 \
    gload_lds16(bg0 + kk, bn + lofs0);                 \
    gload_lds16(bg1 + kk, bn + lofs1);                 \
  }

  STAGE_Q(0);
  STAGE_Q(1);

  const int NS = DIM / BK;  // 12
#pragma unroll
  for (int s = 0; s < NS; ++s) {
    if (s + 2 < NS) {
      STAGE_Q(s + 2);
      asm volatile("s_waitcnt vmcnt(8)" ::: "memory");  // retire stage(s)'s 4
    } else if (s + 1 < NS) {
      asm volatile("s_waitcnt vmcnt(4)" ::: "memory");
    } else {
      asm volatile("s_waitcnt vmcnt(0)" ::: "memory");
    }
    __builtin_amdgcn_s_barrier();          // current buffer globally visible
    const bf16* Ac = Al + (s % 3) * BUFSZ;
    const bf16* Bc = Bl + (s % 3) * BUFSZ;
    bf16x8 af[4], bfr[4];
#pragma unroll
    for (int i = 0; i < 4; ++i) {
      af[i]  = *(const bf16x8*)&Ac[(wm * 64 + i * 16 + l16) * BK + quad * 8];
      bfr[i] = *(const bf16x8*)&Bc[(wn * 64 + i * 16 + l16) * BK + quad * 8];
    }
#pragma unroll
    for (int i = 0; i < 4; ++i)
#pragma unroll
      for (int j = 0; j < 4; ++j)
        acc[i][j] = MFMA16(af[i], bfr[j], acc[i][j]);
    asm volatile("s_waitcnt lgkmcnt(0)" ::: "memory");  // our reads of this buf done
    __builtin_amdgcn_s_barrier();
  }
#undef STAGE_Q
#pragma unroll
  for (int i = 0; i < 4; ++i) {
#pragma unroll
    for (int j = 0; j < 4; ++j) {
#pragma unroll
      for (int rr = 0; rr < 4; ++rr) {
        int row = m0 + wm * 64 + i * 16 + quad * 4 + rr;
        int col = n0 + wn * 64 + j * 16 + l16;
        float v = acc[i][j][rr];
        if (mode == 3) {
          ((float*)out)[(size_t)row * DIM + col] = v + bias[col];
        } else if (mode == 2) {
          int b = row / T2;
          int t = row - b * T2;
          ((bf16*)out)[((size_t)b * DIM + col) * T2P + t] = (bf16)v;
        } else {
          ((bf16*)out)[(size_t)row * DIM + col] = (bf16)(v * scale);
        }
      }
    }
  }
}

__global__ __launch_bounds__(256)
void qkv_gemm_kernel(const bf16* q_act, const bf16* k_act, const bf16* v_act,
                     const bf16* wqb, const bf16* wkb, const bf16* wvb,
                     bf16* Qp, bf16* Kp, bf16* Vtp, float qscale) {
  __shared__ bf16 Al[3 * BUFSZ];   // 24 KB
  __shared__ bf16 Bl[3 * BUFSZ];   // 24 KB
  int bx = blockIdx.x;
  int xp = bx & 7, j = bx >> 3;
  int t = (j / 3) * 24 + xp * 3 + (j % 3);
  if (t >= 882) return;
  const bf16 *A, *Bw; void* out; int mode, ti; float scale;
  if (t < 588)      { A = q_act; Bw = wqb; out = Qp;  mode = 1; scale = qscale; ti = t; }
  else if (t < 735) { A = k_act; Bw = wkb; out = Kp;  mode = 0; scale = 1.f; ti = t - 588; }
  else              { A = v_act; Bw = wvb; out = Vtp; mode = 2; scale = 1.f; ti = t - 735; }
  gemm_body(A, Bw, out, nullptr, mode, scale, (ti / 3) * 128, (ti % 3) * 128, Al, Bl);
}

__global__ __launch_bounds__(256)
void last_gemm_kernel(const bf16* A, const bf16* Bw, float* out, const float* bias) {
  __shared__ bf16 Al[3 * BUFSZ];
  __shared__ bf16 Bl[3 * BUFSZ];
  int bx = blockIdx.x;
  int xp = bx & 7, j = bx >> 3;
  int t = (j / 3) * 24 + xp * 3 + (j % 3);
  if (t >= 588) return;
  gemm_body(A, Bw, out, bias, 3, 1.f, (t / 3) * 128, (t % 3) * 128, Al, Bl);
}

// ---------------- flash attention, S^T/O^T form, 32x32 MFMA, in-register P --------
// R9 (proven): swapped QK^T lands P in the PV B-operand lane; exp2 in-reg ->
// bf16x2 pack -> __shfl_xor(32) -> PV.
// R16: K/V LDS staging DELETED (guide common-mistake #7 / m169: staging
// L2-resident data is pure overhead). Per-(b,h) K/V = 200 KB, L2-pinned by the
// XCD group swizzle; per-iter tile = 16 KB, L1-resident, read by all 4 waves in
// the same window (contiguous 128B per row -> not R13's scattered-16B thrash).
// Zero barriers, zero LDS, zero waitcnt: waves free-run, compiler pipelines
// across iterations. Swizzle algebra collapses: LDS chunk (kk*2+hi)^key of row r
// held global chunk kk*2+hi -> direct read at d (or t) = kk*16+hi*8.
__global__ __launch_bounds__(256, 4)
void attn_kernel(const bf16* __restrict__ Qp, const bf16* __restrict__ Kp,
                 const bf16* __restrict__ Vt, bf16* __restrict__ Ob) {
  int bx = blockIdx.x;
  int xcd = bx & 7, j = bx >> 3;
  int g = xcd + 8 * (j / 25);             // (b,h) group 0..47, fixed per XCD
  int qblk = j % 25;
  int h = g % 6;
  int b = g / 6;
  int tid = threadIdx.x, w = tid >> 6, lane = tid & 63;
  int l32 = lane & 31, hi = lane >> 5;
  int q0w = qblk * 128 + w * 32;

  // Q fragments, B-operand of 32x32x16: n=lane&31=q, k=hi*8+j -> d=kk*16+hi*8+j
  bf16x8 qf[4];
  {
    int qi = q0w + l32;
    qi = qi < T1 ? qi : T1 - 1;
    const bf16* qp = &Qp[((size_t)b * T1 + qi) * DIM + h * 64];
#pragma unroll
    for (int kk = 0; kk < 4; ++kk) qf[kk] = *(const bf16x8*)&qp[kk * 16 + hi * 8];
  }
  floatx16 oacc[2];
  oacc[0] = (floatx16)0.f;
  oacc[1] = (floatx16)0.f;
  float lsum = 0.f;

  // per-lane row bases (row stride fixed across iters; advance by 64 cols/rows)
  const bf16* krow = &Kp[((size_t)b * T2 + l32) * DIM + h * 64];         // + t*DIM
  const bf16* vrow = &Vt[((size_t)b * DIM + h * 64 + l32) * T2P];        // + d*T2P, col t

  for (int it = 0; it < 12; ++it) {
    const int t0 = it * 64;
#pragma unroll
    for (int tt = 0; tt < 2; ++tt) {      // two 32-t tiles
      floatx16 s = (floatx16)0.f;
#pragma unroll
      for (int kk = 0; kk < 4; ++kk) {    // d = kk*16 + hi*8 + j
        bf16x8 kf = *(const bf16x8*)&krow[(size_t)(t0 + tt * 32) * DIM + kk * 16 + hi * 8];
        s = MFMA32(kf, qf[kk], s);
      }
      float e[16];
#pragma unroll
      for (int r = 0; r < 16; ++r) {
        e[r] = __builtin_amdgcn_exp2f(s[r]);
        lsum += e[r];
      }
#pragma unroll
      for (int kkl = 0; kkl < 2; ++kkl) {
        int r0 = kkl * 8;
        u32 pA = pk2(e[r0 + 0], e[r0 + 1]);
        u32 pB = pk2(e[r0 + 2], e[r0 + 3]);
        u32 pC = pk2(e[r0 + 4], e[r0 + 5]);
        u32 pD = pk2(e[r0 + 6], e[r0 + 7]);
        u32 sA = __shfl_xor(pA, 32);
        u32 sB = __shfl_xor(pB, 32);
        u32 sC = __shfl_xor(pC, 32);
        u32 sD = __shfl_xor(pD, 32);
        union { u32 u[4]; bf16x8 v; } pf;
        pf.u[0] = hi ? sC : pA;
        pf.u[1] = hi ? sD : pB;
        pf.u[2] = hi ? pC : sA;
        pf.u[3] = hi ? pD : sB;
        int kk = tt * 2 + kkl;            // t-chunk for V: t = t0 + kk*16 + hi*8 + j
#pragma unroll
        for (int dt = 0; dt < 2; ++dt) {
          bf16x8 vf = *(const bf16x8*)&vrow[(size_t)(dt * 32) * T2P + t0 + kk * 16 + hi * 8];
          oacc[dt] = MFMA32(vf, pf.v, oacc[dt]);
        }
      }
    }
  }
  // tail: t 768..783 (16 rows land in reg group r0..7; clamped rows never consumed)
  {
    int tq = 768 + l32;
    tq = tq < T2 ? tq : T2 - 1;
    const bf16* kp2 = &Kp[((size_t)b * T2 + tq) * DIM + h * 64];
    floatx16 s = (floatx16)0.f;
#pragma unroll
    for (int kk = 0; kk < 4; ++kk) {
      bf16x8 kf = *(const bf16x8*)&kp2[kk * 16 + hi * 8];
      s = MFMA32(kf, qf[kk], s);
    }
    float e[8];
#pragma unroll
    for (int r = 0; r < 8; ++r) {
      e[r] = __builtin_amdgcn_exp2f(s[r]);
      lsum += e[r];
    }
    u32 pA = pk2(e[0], e[1]);
    u32 pB = pk2(e[2], e[3]);
    u32 pC = pk2(e[4], e[5]);
    u32 pD = pk2(e[6], e[7]);
    u32 sA = __shfl_xor(pA, 32);
    u32 sB = __shfl_xor(pB, 32);
    u32 sC = __shfl_xor(pC, 32);
    u32 sD = __shfl_xor(pD, 32);
    union { u32 u[4]; bf16x8 v; } pf;
    pf.u[0] = hi ? sC : pA;
    pf.u[1] = hi ? sD : pB;
    pf.u[2] = hi ? pC : sA;
    pf.u[3] = hi ? pD : sB;
#pragma unroll
    for (int dt = 0; dt < 2; ++dt) {
      const bf16* vp2 = &Vt[((size_t)b * DIM + h * 64 + dt * 32 + l32) * T2P + 768 + hi * 8];
      bf16x8 vf = *(const bf16x8*)vp2;
      oacc[dt] = MFMA32(vf, pf.v, oacc[dt]);
    }
  }
  // epilogue
  lsum += __shfl_xor(lsum, 32);
  float inv = 1.f / lsum;
  int qg = q0w + l32;
  if (qg < T1) {
    bf16* op = &Ob[((size_t)b * T1 + qg) * DIM + h * 64];
#pragma unroll
    for (int dt = 0; dt < 2; ++dt) {
#pragma unroll
      for (int gr = 0; gr < 4; ++gr) {
        bf16x4 ov = (bf16x4){(bf16)(oacc[dt][gr * 4 + 0] * inv),
                             (bf16)(oacc[dt][gr * 4 + 1] * inv),
                             (bf16)(oacc[dt][gr * 4 + 2] * inv),
                             (bf16)(oacc[dt][gr * 4 + 3] * inv)};
        *(bf16x4*)&op[dt * 32 + gr * 8 + hi * 4] = ov;
      }
    }
  }
}

// ---------------- launch ----------------
extern "C" void kernel_launch(void* const* d_in, const int* in_sizes, int n_in,
                              void* d_out, int out_size, void* d_ws, size_t ws_size,
                              hipStream_t stream) {
  (void)in_sizes; (void)n_in; (void)out_size; (void)ws_size;
  const float* x      = (const float*)d_in[0];
  const float* conv_q = (const float*)d_in[3];
  const float* bnq_s  = (const float*)d_in[4];
  const float* bnq_b  = (const float*)d_in[5];
  const float* bnq_m  = (const float*)d_in[6];
  const float* bnq_v  = (const float*)d_in[7];
  const float* conv_k = (const float*)d_in[8];
  const float* bnk_s  = (const float*)d_in[9];
  const float* bnk_b  = (const float*)d_in[10];
  const float* bnk_m  = (const float*)d_in[11];
  const float* bnk_v  = (const float*)d_in[12];
  const float* conv_v = (const float*)d_in[13];
  const float* bnv_s  = (const float*)d_in[14];
  const float* bnv_b  = (const float*)d_in[15];
  const float* bnv_m  = (const float*)d_in[16];
  const float* bnv_v  = (const float*)d_in[17];
  const float* wq     = (const float*)d_in[18];
  const float* wk     = (const float*)d_in[19];
  const float* wv     = (const float*)d_in[20];
  const float* wl     = (const float*)d_in[21];
  const float* b_last = (const float*)d_in[22];

  char* ws = (char*)d_ws;
  bf16* q_act = (bf16*)(ws + 0);               // 19267584; reused as attention output
  bf16* k_act = (bf16*)(ws + 19267584);        // 4816896
  bf16* v_act = (bf16*)(ws + 24084480);        // 4816896
  bf16* Qp    = (bf16*)(ws + 28901376);        // 19267584 (pre-scaled by SCALE*log2e)
  bf16* Kp    = (bf16*)(ws + 48168960);        // 4816896
  bf16* Vtp   = (bf16*)(ws + 52985856);        // 8*384*832*2 = 5111808  [B][384][T2P]
  bf16* wqb   = (bf16*)(ws + 58097664);        // 294912 each, x4
  bf16* wkb   = wqb + 147456;
  bf16* wvb   = wkb + 147456;
  bf16* wlb   = wvb + 147456;

  const float QSCALE = 0.05103103630798288f * 1.4426950408889634f;  // 384^-0.5 * log2e

  conv_fused_kernel<<<B_ * 14 * 14, DIM, 0, stream>>>(
      x,
      conv_q, bnq_s, bnq_b, bnq_m, bnq_v,
      conv_k, bnk_s, bnk_b, bnk_m, bnk_v,
      conv_v, bnv_s, bnv_b, bnv_m, bnv_v,
      q_act, k_act, v_act,
      wq, wk, wv, wl, wqb, wkb, wvb, wlb);

  qkv_gemm_kernel<<<888, 256, 0, stream>>>(q_act, k_act, v_act, wqb, wkb, wvb,
                                           Qp, Kp, Vtp, QSCALE);

  attn_kernel<<<25 * 6 * B_, 256, 0, stream>>>(Qp, Kp, Vtp, q_act);

  last_gemm_kernel<<<600, 256, 0, stream>>>(q_act, wlb, (float*)d_out, b_last);
}

// Round 12
// 230.707 us; speedup vs baseline: 1.3816x; 1.3816x over previous
//
#include <hip/hip_runtime.h>
#include <hip/hip_bf16.h>

typedef __bf16 bf16;
typedef __attribute__((ext_vector_type(8))) __bf16 bf16x8;
typedef __attribute__((ext_vector_type(4))) __bf16 bf16x4;
typedef __attribute__((ext_vector_type(2))) __bf16 bf16x2;
typedef __attribute__((ext_vector_type(4))) float floatx4;
typedef __attribute__((ext_vector_type(16))) float floatx16;
typedef unsigned int u32;

#define MFMA16(a, b, c) __builtin_amdgcn_mfma_f32_16x16x32_bf16((a), (b), (c), 0, 0, 0)
#define MFMA32(a, b, c) __builtin_amdgcn_mfma_f32_32x32x16_bf16((a), (b), (c), 0, 0, 0)

#define DIM 384
#define T1 3136   // 56*56
#define T2 784    // 28*28
#define T2P 832   // padded t for Vt columns
#define B_ 8
#define EPSV 1e-5f

__device__ __forceinline__ void gload_lds16(const bf16* g, bf16* l) {
  __builtin_amdgcn_global_load_lds(
      (const __attribute__((address_space(1))) void*)g,
      (__attribute__((address_space(3))) void*)l, 16, 0, 0);
}

__device__ __forceinline__ u32 pk2(float a, float b) {
  bf16x2 t = (bf16x2){(bf16)a, (bf16)b};
  return *reinterpret_cast<u32*>(&t);
}

// ---------------- fused depthwise convs + BN + wcvt, 4x4 spatial tile --------------
// R14 (proven: -12 us): 4x4 output tile, halo in[6][6], kv 2x2 in every block.
__global__ void conv_fused_kernel(const float* __restrict__ x,
    const float* __restrict__ wqc, const float* __restrict__ gq, const float* __restrict__ bq,
    const float* __restrict__ mq, const float* __restrict__ vq,
    const float* __restrict__ wkc, const float* __restrict__ gk, const float* __restrict__ bk,
    const float* __restrict__ mk, const float* __restrict__ vk,
    const float* __restrict__ wvc, const float* __restrict__ gv, const float* __restrict__ bv,
    const float* __restrict__ mv, const float* __restrict__ vvv,
    bf16* __restrict__ qout, bf16* __restrict__ kout, bf16* __restrict__ vout,
    const float* __restrict__ w0, const float* __restrict__ w1,
    const float* __restrict__ w2, const float* __restrict__ w3,
    bf16* __restrict__ d0, bf16* __restrict__ d1,
    bf16* __restrict__ d2, bf16* __restrict__ d3) {
  int blk = blockIdx.x;
  int c = threadIdx.x;           // 0..383
  int gid = blk * DIM + c;
  if (gid < 147456) {            // folded weight conversion (first 384 blocks)
    d0[gid] = (bf16)w0[gid]; d1[gid] = (bf16)w1[gid];
    d2[gid] = (bf16)w2[gid]; d3[gid] = (bf16)w3[gid];
  }
  int xg = blk % 14;
  int yg = (blk / 14) % 14;
  int b = blk / 196;
  int x0 = xg * 4, y0 = yg * 4;
  const float* xb = x + (size_t)b * T1 * DIM;
  float in[6][6];
#pragma unroll
  for (int r = 0; r < 6; ++r) {
    int yy = y0 + r - 1;
#pragma unroll
    for (int cc = 0; cc < 6; ++cc) {
      int xc = x0 + cc - 1;
      in[r][cc] = (yy >= 0 && yy < 56 && xc >= 0 && xc < 56)
                      ? xb[(yy * 56 + xc) * DIM + c] : 0.f;
    }
  }
  // q path: 4x4 outputs
  {
    float wr[9];
#pragma unroll
    for (int i = 0; i < 9; ++i) wr[i] = wqc[c * 9 + i];
    float a = rsqrtf(vq[c] + EPSV) * gq[c];
    float bia = bq[c] - mq[c] * a;
#pragma unroll
    for (int py = 0; py < 4; ++py) {
#pragma unroll
      for (int px = 0; px < 4; ++px) {
        float s = 0.f;
#pragma unroll
        for (int r = 0; r < 3; ++r)
#pragma unroll
          for (int dx = 0; dx < 3; ++dx) s += in[py + r][px + dx] * wr[r * 3 + dx];
        qout[((size_t)b * T1 + (y0 + py) * 56 + x0 + px) * DIM + c] = (bf16)(s * a + bia);
      }
    }
  }
  // kv path: 2x2 stride-2 outputs (y0, x0 even)
  {
    float wk9[9], wv9[9];
#pragma unroll
    for (int i = 0; i < 9; ++i) { wk9[i] = wkc[c * 9 + i]; wv9[i] = wvc[c * 9 + i]; }
    float ak = rsqrtf(vk[c] + EPSV) * gk[c];
    float av = rsqrtf(vvv[c] + EPSV) * gv[c];
    float bik = bk[c] - mk[c] * ak;
    float biv = bv[c] - mv[c] * av;
#pragma unroll
    for (int py = 0; py < 2; ++py) {
#pragma unroll
      for (int px = 0; px < 2; ++px) {
        float sk = 0.f, sv = 0.f;
#pragma unroll
        for (int r = 0; r < 3; ++r)
#pragma unroll
          for (int dx = 0; dx < 3; ++dx) {
            float xv = in[2 * py + r][2 * px + dx];
            sk += xv * wk9[r * 3 + dx];
            sv += xv * wv9[r * 3 + dx];
          }
        size_t o = ((size_t)b * T2 + (y0 / 2 + py) * 28 + (x0 / 2 + px)) * DIM + c;
        kout[o] = (bf16)(sk * ak + bik);
        vout[o] = (bf16)(sv * av + biv);
      }
    }
  }
}

// ---------------- shared GEMM body: C[128,128] tile of A[M,384] @ W[384,384]^T ------
// R15 (best measured): depth-2 staging, triple-buffered LDS, vmcnt(8) steady state.
#define BK 32
#define BUFSZ (128 * BK)
__device__ __forceinline__
void gemm_body(const bf16* A, const bf16* Bw, void* out, const float* bias,
               int mode, float scale, int m0, int n0, bf16* Al, bf16* Bl) {
  int tid = threadIdx.x;
  int w = tid >> 6, lane = tid & 63;
  int wm = w >> 1, wn = w & 1;
  int l16 = lane & 15, quad = lane >> 4;
  floatx4 acc[4][4];
#pragma unroll
  for (int i = 0; i < 4; ++i)
#pragma unroll
    for (int j = 0; j < 4; ++j) acc[i][j] = (floatx4){0.f, 0.f, 0.f, 0.f};

  int srow = w * 32 + (lane >> 2);
  int scol = (lane & 3) * 8;
  const bf16* ag0 = &A[(size_t)(m0 + srow) * DIM + scol];
  const bf16* ag1 = ag0 + (size_t)16 * DIM;
  const bf16* bg0 = &Bw[(size_t)(n0 + srow) * DIM + scol];
  const bf16* bg1 = bg0 + (size_t)16 * DIM;
  int lofs0 = (w * 32) * BK;
  int lofs1 = (w * 32 + 16) * BK;

#define STAGE_Q(s) {                                   \
    bf16* an = Al + ((s) % 3) * BUFSZ;                 \
    bf16* bn = Bl + ((s) % 3) * BUFSZ;                 \
    const int kk = (s) * BK;                           \
    gload_lds16(ag0 + kk, an + lofs0);                 \
    gload_lds16(ag1 + kk, an + lofs1);                 \
    gload_lds16(bg0 + kk, bn + lofs0);                 \
    gload_lds16(bg1 + kk, bn + lofs1);                 \
  }

  STAGE_Q(0);
  STAGE_Q(1);

  const int NS = DIM / BK;  // 12
#pragma unroll
  for (int s = 0; s < NS; ++s) {
    if (s + 2 < NS) {
      STAGE_Q(s + 2);
      asm volatile("s_waitcnt vmcnt(8)" ::: "memory");  // retire stage(s)'s 4
    } else if (s + 1 < NS) {
      asm volatile("s_waitcnt vmcnt(4)" ::: "memory");
    } else {
      asm volatile("s_waitcnt vmcnt(0)" ::: "memory");
    }
    __builtin_amdgcn_s_barrier();          // current buffer globally visible
    const bf16* Ac = Al + (s % 3) * BUFSZ;
    const bf16* Bc = Bl + (s % 3) * BUFSZ;
    bf16x8 af[4], bfr[4];
#pragma unroll
    for (int i = 0; i < 4; ++i) {
      af[i]  = *(const bf16x8*)&Ac[(wm * 64 + i * 16 + l16) * BK + quad * 8];
      bfr[i] = *(const bf16x8*)&Bc[(wn * 64 + i * 16 + l16) * BK + quad * 8];
    }
#pragma unroll
    for (int i = 0; i < 4; ++i)
#pragma unroll
      for (int j = 0; j < 4; ++j)
        acc[i][j] = MFMA16(af[i], bfr[j], acc[i][j]);
    asm volatile("s_waitcnt lgkmcnt(0)" ::: "memory");  // our reads of this buf done
    __builtin_amdgcn_s_barrier();
  }
#undef STAGE_Q
#pragma unroll
  for (int i = 0; i < 4; ++i) {
#pragma unroll
    for (int j = 0; j < 4; ++j) {
#pragma unroll
      for (int rr = 0; rr < 4; ++rr) {
        int row = m0 + wm * 64 + i * 16 + quad * 4 + rr;
        int col = n0 + wn * 64 + j * 16 + l16;
        float v = acc[i][j][rr];
        if (mode == 3) {
          ((float*)out)[(size_t)row * DIM + col] = v + bias[col];
        } else if (mode == 2) {
          int b = row / T2;
          int t = row - b * T2;
          ((bf16*)out)[((size_t)b * DIM + col) * T2P + t] = (bf16)v;
        } else {
          ((bf16*)out)[(size_t)row * DIM + col] = (bf16)(v * scale);
        }
      }
    }
  }
}

__global__ __launch_bounds__(256)
void qkv_gemm_kernel(const bf16* q_act, const bf16* k_act, const bf16* v_act,
                     const bf16* wqb, const bf16* wkb, const bf16* wvb,
                     bf16* Qp, bf16* Kp, bf16* Vtp, float qscale) {
  __shared__ bf16 Al[3 * BUFSZ];   // 24 KB
  __shared__ bf16 Bl[3 * BUFSZ];   // 24 KB
  int bx = blockIdx.x;
  int xp = bx & 7, j = bx >> 3;
  int t = (j / 3) * 24 + xp * 3 + (j % 3);
  if (t >= 882) return;
  const bf16 *A, *Bw; void* out; int mode, ti; float scale;
  if (t < 588)      { A = q_act; Bw = wqb; out = Qp;  mode = 1; scale = qscale; ti = t; }
  else if (t < 735) { A = k_act; Bw = wkb; out = Kp;  mode = 0; scale = 1.f; ti = t - 588; }
  else              { A = v_act; Bw = wvb; out = Vtp; mode = 2; scale = 1.f; ti = t - 735; }
  gemm_body(A, Bw, out, nullptr, mode, scale, (ti / 3) * 128, (ti % 3) * 128, Al, Bl);
}

__global__ __launch_bounds__(256)
void last_gemm_kernel(const bf16* A, const bf16* Bw, float* out, const float* bias) {
  __shared__ bf16 Al[3 * BUFSZ];
  __shared__ bf16 Bl[3 * BUFSZ];
  int bx = blockIdx.x;
  int xp = bx & 7, j = bx >> 3;
  int t = (j / 3) * 24 + xp * 3 + (j % 3);
  if (t >= 588) return;
  gemm_body(A, Bw, out, bias, 3, 1.f, (t / 3) * 128, (t % 3) * 128, Al, Bl);
}

// ---------------- flash attention, S^T/O^T form, 32x32 MFMA, in-register P --------
// R9 (proven): swapped QK^T lands P in the PV B-operand lane; exp2 in-reg ->
// bf16x2 pack -> __shfl_xor(32) -> PV. No P LDS. 16 KB LDS, launch_bounds(256,4).
// R16 lesson (reverted): K/V LDS staging is LOAD-BEARING — fragment reads are
// row-scattered (32 lanes x 32 distinct 768B-strided rows per instr); staging
// converts coalesced 128B segments into that pattern. Direct-global was 3x slower.
__global__ __launch_bounds__(256, 4)
void attn_kernel(const bf16* __restrict__ Qp, const bf16* __restrict__ Kp,
                 const bf16* __restrict__ Vt, bf16* __restrict__ Ob) {
  __shared__ bf16 Kl[64 * 64];            // [t][d], chunk-XOR swizzled (8 KB)
  __shared__ bf16 Vl[64 * 64];            // [d][t], chunk-XOR swizzled (8 KB)
  int bx = blockIdx.x;
  int xcd = bx & 7, j = bx >> 3;
  int g = xcd + 8 * (j / 25);             // (b,h) group 0..47, fixed per XCD
  int qblk = j % 25;
  int h = g % 6;
  int b = g / 6;
  int tid = threadIdx.x, w = tid >> 6, lane = tid & 63;
  int l32 = lane & 31, hi = lane >> 5;
  int q0w = qblk * 128 + w * 32;

  // Q fragments, B-operand of 32x32x16: n=lane&31=q, k=hi*8+j -> d=kk*16+hi*8+j
  bf16x8 qf[4];
  {
    int qi = q0w + l32;
    qi = qi < T1 ? qi : T1 - 1;
    const bf16* qp = &Qp[((size_t)b * T1 + qi) * DIM + h * 64];
#pragma unroll
    for (int kk = 0; kk < 4; ++kk) qf[kk] = *(const bf16x8*)&qp[kk * 16 + hi * 8];
  }
  floatx16 oacc[2];
  oacc[0] = (floatx16)0.f;
  oacc[1] = (floatx16)0.f;
  float lsum = 0.f;

  int rsub = lane >> 3;
  int chnk = (lane & 7) ^ rsub;
  const bf16* kg0 = &Kp[((size_t)b * T2 + w * 16 + rsub) * DIM + h * 64 + chnk * 8];
  const bf16* kg1 = kg0 + (size_t)8 * DIM;
  const bf16* vg0 = &Vt[((size_t)b * DIM + h * 64 + w * 16 + rsub) * T2P + chnk * 8];
  const bf16* vg1 = vg0 + (size_t)8 * T2P;
  bf16* kl0 = &Kl[(w * 16) * 64];
  bf16* kl1 = &Kl[(w * 16 + 8) * 64];
  bf16* vl0 = &Vl[(w * 16) * 64];
  bf16* vl1 = &Vl[(w * 16 + 8) * 64];

  int key = lane & 7;                     // fragment-read swizzle key (= row&7)

  for (int it = 0; it < 12; ++it) {
    __syncthreads();                      // prev iter's tile reads done
    gload_lds16(kg0, kl0);
    gload_lds16(kg1, kl1);
    gload_lds16(vg0, vl0);
    gload_lds16(vg1, vl1);
    __syncthreads();                      // drains vmcnt: tiles ready
#pragma unroll
    for (int tt = 0; tt < 2; ++tt) {      // two 32-t tiles
      floatx16 s = (floatx16)0.f;
#pragma unroll
      for (int kk = 0; kk < 4; ++kk) {    // d = kk*16 + hi*8 + j
        bf16x8 kf = *(const bf16x8*)&Kl[(tt * 32 + l32) * 64 + ((kk * 2 + hi) ^ key) * 8];
        s = MFMA32(kf, qf[kk], s);
      }
      float e[16];
#pragma unroll
      for (int r = 0; r < 16; ++r) {
        e[r] = __builtin_amdgcn_exp2f(s[r]);
        lsum += e[r];
      }
#pragma unroll
      for (int kkl = 0; kkl < 2; ++kkl) {
        int r0 = kkl * 8;
        u32 pA = pk2(e[r0 + 0], e[r0 + 1]);
        u32 pB = pk2(e[r0 + 2], e[r0 + 3]);
        u32 pC = pk2(e[r0 + 4], e[r0 + 5]);
        u32 pD = pk2(e[r0 + 6], e[r0 + 7]);
        u32 sA = __shfl_xor(pA, 32);
        u32 sB = __shfl_xor(pB, 32);
        u32 sC = __shfl_xor(pC, 32);
        u32 sD = __shfl_xor(pD, 32);
        union { u32 u[4]; bf16x8 v; } pf;
        pf.u[0] = hi ? sC : pA;
        pf.u[1] = hi ? sD : pB;
        pf.u[2] = hi ? pC : sA;
        pf.u[3] = hi ? pD : sB;
        int kk = tt * 2 + kkl;            // t-chunk for V: t = kk*16 + hi*8 + j
#pragma unroll
        for (int dt = 0; dt < 2; ++dt) {
          bf16x8 vf = *(const bf16x8*)&Vl[(dt * 32 + l32) * 64 + ((kk * 2 + hi) ^ key) * 8];
          oacc[dt] = MFMA32(vf, pf.v, oacc[dt]);
        }
      }
    }
    kg0 += (size_t)64 * DIM; kg1 += (size_t)64 * DIM;
    vg0 += 64; vg1 += 64;
  }
  // tail: t 768..783 (16 rows land in reg group r0..7; clamped rows never consumed)
  {
    int tq = 768 + l32;
    tq = tq < T2 ? tq : T2 - 1;
    const bf16* kp2 = &Kp[((size_t)b * T2 + tq) * DIM + h * 64];
    floatx16 s = (floatx16)0.f;
#pragma unroll
    for (int kk = 0; kk < 4; ++kk) {
      bf16x8 kf = *(const bf16x8*)&kp2[kk * 16 + hi * 8];
      s = MFMA32(kf, qf[kk], s);
    }
    float e[8];
#pragma unroll
    for (int r = 0; r < 8; ++r) {
      e[r] = __builtin_amdgcn_exp2f(s[r]);
      lsum += e[r];
    }
    u32 pA = pk2(e[0], e[1]);
    u32 pB = pk2(e[2], e[3]);
    u32 pC = pk2(e[4], e[5]);
    u32 pD = pk2(e[6], e[7]);
    u32 sA = __shfl_xor(pA, 32);
    u32 sB = __shfl_xor(pB, 32);
    u32 sC = __shfl_xor(pC, 32);
    u32 sD = __shfl_xor(pD, 32);
    union { u32 u[4]; bf16x8 v; } pf;
    pf.u[0] = hi ? sC : pA;
    pf.u[1] = hi ? sD : pB;
    pf.u[2] = hi ? pC : sA;
    pf.u[3] = hi ? pD : sB;
#pragma unroll
    for (int dt = 0; dt < 2; ++dt) {
      const bf16* vp2 = &Vt[((size_t)b * DIM + h * 64 + dt * 32 + l32) * T2P + 768 + hi * 8];
      bf16x8 vf = *(const bf16x8*)vp2;
      oacc[dt] = MFMA32(vf, pf.v, oacc[dt]);
    }
  }
  // epilogue
  lsum += __shfl_xor(lsum, 32);
  float inv = 1.f / lsum;
  int qg = q0w + l32;
  if (qg < T1) {
    bf16* op = &Ob[((size_t)b * T1 + qg) * DIM + h * 64];
#pragma unroll
    for (int dt = 0; dt < 2; ++dt) {
#pragma unroll
      for (int gr = 0; gr < 4; ++gr) {
        bf16x4 ov = (bf16x4){(bf16)(oacc[dt][gr * 4 + 0] * inv),
                             (bf16)(oacc[dt][gr * 4 + 1] * inv),
                             (bf16)(oacc[dt][gr * 4 + 2] * inv),
                             (bf16)(oacc[dt][gr * 4 + 3] * inv)};
        *(bf16x4*)&op[dt * 32 + gr * 8 + hi * 4] = ov;
      }
    }
  }
}

// ---------------- launch ----------------
extern "C" void kernel_launch(void* const* d_in, const int* in_sizes, int n_in,
                              void* d_out, int out_size, void* d_ws, size_t ws_size,
                              hipStream_t stream) {
  (void)in_sizes; (void)n_in; (void)out_size; (void)ws_size;
  const float* x      = (const float*)d_in[0];
  const float* conv_q = (const float*)d_in[3];
  const float* bnq_s  = (const float*)d_in[4];
  const float* bnq_b  = (const float*)d_in[5];
  const float* bnq_m  = (const float*)d_in[6];
  const float* bnq_v  = (const float*)d_in[7];
  const float* conv_k = (const float*)d_in[8];
  const float* bnk_s  = (const float*)d_in[9];
  const float* bnk_b  = (const float*)d_in[10];
  const float* bnk_m  = (const float*)d_in[11];
  const float* bnk_v  = (const float*)d_in[12];
  const float* conv_v = (const float*)d_in[13];
  const float* bnv_s  = (const float*)d_in[14];
  const float* bnv_b  = (const float*)d_in[15];
  const float* bnv_m  = (const float*)d_in[16];
  const float* bnv_v  = (const float*)d_in[17];
  const float* wq     = (const float*)d_in[18];
  const float* wk     = (const float*)d_in[19];
  const float* wv     = (const float*)d_in[20];
  const float* wl     = (const float*)d_in[21];
  const float* b_last = (const float*)d_in[22];

  char* ws = (char*)d_ws;
  bf16* q_act = (bf16*)(ws + 0);               // 19267584; reused as attention output
  bf16* k_act = (bf16*)(ws + 19267584);        // 4816896
  bf16* v_act = (bf16*)(ws + 24084480);        // 4816896
  bf16* Qp    = (bf16*)(ws + 28901376);        // 19267584 (pre-scaled by SCALE*log2e)
  bf16* Kp    = (bf16*)(ws + 48168960);        // 4816896
  bf16* Vtp   = (bf16*)(ws + 52985856);        // 8*384*832*2 = 5111808  [B][384][T2P]
  bf16* wqb   = (bf16*)(ws + 58097664);        // 294912 each, x4
  bf16* wkb   = wqb + 147456;
  bf16* wvb   = wkb + 147456;
  bf16* wlb   = wvb + 147456;

  const float QSCALE = 0.05103103630798288f * 1.4426950408889634f;  // 384^-0.5 * log2e

  conv_fused_kernel<<<B_ * 14 * 14, DIM, 0, stream>>>(
      x,
      conv_q, bnq_s, bnq_b, bnq_m, bnq_v,
      conv_k, bnk_s, bnk_b, bnk_m, bnk_v,
      conv_v, bnv_s, bnv_b, bnv_m, bnv_v,
      q_act, k_act, v_act,
      wq, wk, wv, wl, wqb, wkb, wvb, wlb);

  qkv_gemm_kernel<<<888, 256, 0, stream>>>(q_act, k_act, v_act, wqb, wkb, wvb,
                                           Qp, Kp, Vtp, QSCALE);

  attn_kernel<<<25 * 6 * B_, 256, 0, stream>>>(Qp, Kp, Vtp, q_act);

  last_gemm_kernel<<<600, 256, 0, stream>>>(q_act, wlb, (float*)d_out, b_last);
}